// Round 9
// baseline (69.885 us; speedup 1.0000x reference)
//
#include <hip/hip_runtime.h>
#include <math.h>

#define L      2048
#define DDIM   512
#define NBATCH 8
#define BM     128
#define BN     128
#define BK     32
#define NKT    (DDIM / BK)               // 16 K-tiles
#define NTILE  (L / BM)                  // 16
#define NPAIR  (NTILE * (NTILE + 1) / 2) // 136
#define TOTAL_BLOCKS (NBATCH * NPAIR)    // 1088

#define ALPHA  0.1f
#define BETA   0.3f
#define MARGIN 2.0f

typedef _Float16 f16x8 __attribute__((ext_vector_type(8)));
typedef __attribute__((ext_vector_type(16))) float f32x16;

// Buffer (16 KB): A[128 rows x 64B] then B[128 rows x 64B].
// Row = 4 chunks of 8 f16 (16B); physical chunk = logical ^ (row & 3).
// 4 buffers (64 KB) -> depth-2 tile prefetch, vmcnt never drains in-loop.
#define TILE_SH 4096       // f16 per tile (8 KB)
#define BUFSZ   8192       // f16 per buffer (16 KB)

#define GLOAD_LDS16(g, l) __builtin_amdgcn_global_load_lds(              \
    (const __attribute__((address_space(1))) unsigned int*)(g),          \
    (__attribute__((address_space(3))) unsigned int*)(l), 16, 0, 0)

// ---------------------------------------------------------------------------
// Kernel 1: fp32 -> fp16 + per-row squared norms (exact fp32).
// ---------------------------------------------------------------------------
__global__ __launch_bounds__(256) void conv_kernel(const float* __restrict__ pred,
                                                   _Float16* __restrict__ h,
                                                   float* __restrict__ sq) {
    int w    = threadIdx.x >> 6;
    int lane = threadIdx.x & 63;
    int row  = blockIdx.x * 4 + w;
    const float* p = pred + (size_t)row * DDIM + lane * 8;
    float4 v0 = *(const float4*)(p);
    float4 v1 = *(const float4*)(p + 4);
    float vals[8] = {v0.x, v0.y, v0.z, v0.w, v1.x, v1.y, v1.z, v1.w};
    f16x8 hv;
    float s = 0.0f;
    #pragma unroll
    for (int i = 0; i < 8; ++i) {
        float x = vals[i];
        s = fmaf(x, x, s);
        hv[i] = (_Float16)x;
    }
    *(f16x8*)(h + (size_t)row * DDIM + lane * 8) = hv;
    #pragma unroll
    for (int off = 32; off > 0; off >>= 1) s += __shfl_down(s, off);
    if (lane == 0) sq[row] = s;
}

// ---------------------------------------------------------------------------
// Kernel 2: fp16 Gram GEMM + fused loss + per-block reduction.
// 128x128 tile, 4 waves (2x2 of 64x64), mfma_f32_32x32x16_f16, BK=32.
// 16 K-tiles; per tile: 4 gload_lds (stage kt+2) + 8 ds_read_b128 + 8 MFMA
// per wave, ONE s_barrier, counted s_waitcnt vmcnt(4) (0 only on last tile).
// 4 LDS buffers: writer of buf[(kt+2)&3] is 2 barriers past its last reader.
// ---------------------------------------------------------------------------
__global__ __launch_bounds__(256, 2) void loss_kernel(
        const _Float16* __restrict__ h,
        const int*   __restrict__ seg,
        const float* __restrict__ sq,
        double*      __restrict__ partials) {
    __shared__ _Float16 smem[4 * BUFSZ];   // 64 KB
    __shared__ double wred[4];

    int bid = blockIdx.x;
    int n = bid & 7;            // batch -> XCD round-robin (L2 locality)
    int p = bid >> 3;           // 0..135
    int tj = 0;
    while (true) {
        int rl2 = NTILE - tj;
        if (p < rl2) break;
        p -= rl2;
        ++tj;
    }
    int tk = tj + p;
    int j0 = tj * BM, k0 = tk * BN;

    int t    = threadIdx.x;
    int w    = t >> 6;          // 0..3
    int lane = t & 63;
    int wr   = w >> 1, wc = w & 1;     // 64x64 quadrant
    int l31  = lane & 31;
    int hsel = lane >> 5;              // 0/1: k-halfslice of the frag

    const _Float16* baseH = h + (size_t)n * L * DDIM;

    // staging: inst covers 16 rows x 64B; lane -> row rl4 = lane>>2,
    // phys chunk = lane&3, logical chunk lc = (lane&3) ^ (rl4 & 3).
    // Wave w stages A-insts {2w,2w+1} and B-insts {2w,2w+1}: 4 gload_lds.
    int rl4 = lane >> 2;
    int lc  = (lane & 3) ^ (rl4 & 3);
    const _Float16* srcA = baseH + (size_t)(j0 + rl4) * DDIM + lc * 8;
    const _Float16* srcB = baseH + (size_t)(k0 + rl4) * DDIM + lc * 8;

    f32x16 acc[2][2];
    #pragma unroll
    for (int m = 0; m < 2; ++m)
        #pragma unroll
        for (int nn = 0; nn < 2; ++nn)
            #pragma unroll
            for (int r = 0; r < 16; ++r) acc[m][nn][r] = 0.0f;

    #define STAGE(kt)                                                         \
    {                                                                         \
        _Float16* _A = smem + ((kt) & 3) * BUFSZ;                             \
        _Float16* _B = _A + TILE_SH;                                          \
        _Pragma("unroll")                                                     \
        for (int q = 0; q < 2; ++q) {                                         \
            int inst = w * 2 + q;                                             \
            GLOAD_LDS16(srcA + (size_t)(inst * 16) * DDIM + (kt) * BK,        \
                        _A + inst * 512);                                     \
            GLOAD_LDS16(srcB + (size_t)(inst * 16) * DDIM + (kt) * BK,        \
                        _B + inst * 512);                                     \
        }                                                                     \
    }

    STAGE(0);
    STAGE(1);

    #pragma unroll
    for (int kt = 0; kt < NKT; ++kt) {
        // own loads for tile kt done (4 of tile kt+1 stay in flight),
        // then barrier -> everyone's tile-kt loads are complete.
        if (kt + 1 < NKT) {
            asm volatile("s_waitcnt vmcnt(4)" ::: "memory");
        } else {
            asm volatile("s_waitcnt vmcnt(0)" ::: "memory");
        }
        __builtin_amdgcn_s_barrier();
        if (kt + 2 < NKT) STAGE(kt + 2);     // issue early: 2-tile latency cover

        const _Float16* A = smem + (kt & 3) * BUFSZ;
        const _Float16* B = A + TILE_SH;

        #pragma unroll
        for (int ks = 0; ks < 2; ++ks) {     // two K=16 steps
            int c = ks * 2 + hsel;           // logical chunk 0..3
            f16x8 af[2], bf[2];
            #pragma unroll
            for (int m = 0; m < 2; ++m) {
                int R = wr * 64 + m * 32 + l31;
                af[m] = *(const f16x8*)&A[R * 32 + ((c ^ (R & 3)) << 3)];
            }
            #pragma unroll
            for (int nn = 0; nn < 2; ++nn) {
                int R = wc * 64 + nn * 32 + l31;
                bf[nn] = *(const f16x8*)&B[R * 32 + ((c ^ (R & 3)) << 3)];
            }
            __builtin_amdgcn_s_setprio(1);
            #pragma unroll
            for (int m = 0; m < 2; ++m)
                #pragma unroll
                for (int nn = 0; nn < 2; ++nn)
                    acc[m][nn] = __builtin_amdgcn_mfma_f32_32x32x16_f16(
                        af[m], bf[nn], acc[m][nn], 0, 0, 0);
            __builtin_amdgcn_s_setprio(0);
        }
    }

    // ------------------- fused loss epilogue -------------------
    // 32x32 C/D layout: col = lane&31, row = (reg&3) + 8*(reg>>2) + 4*(lane>>5)
    const int*   segb = seg + n * L;
    const float* sqb  = sq + n * L;

    float lsum = 0.0f;
    #pragma unroll
    for (int nn = 0; nn < 2; ++nn) {
        int k = k0 + wc * 64 + nn * 32 + l31;
        float sqk = sqb[k];
        int   sgk = segb[k];
        #pragma unroll
        for (int m = 0; m < 2; ++m)
            #pragma unroll
            for (int r = 0; r < 16; ++r) {
                int j = j0 + wr * 64 + m * 32 + (r & 3) + 8 * (r >> 2) + 4 * hsel;
                float inner = acc[m][nn][r];
                float d2 = fmaxf(sqb[j] + sqk - 2.0f * inner, 0.0f);
                float v;
                if (segb[j] == sgk) {
                    v = ALPHA * d2;
                } else {
                    float dist = sqrtf(d2);
                    float hg = fmaxf(MARGIN - dist, 0.0f);
                    v = BETA * hg * hg;
                }
                lsum += v;
            }
    }

    // per-wave shuffle reduction (no LDS tree -> no bank conflicts)
    double wgt = (tj == tk) ? 1.0 : 2.0;
    double dsum = (double)lsum * wgt;
    #pragma unroll
    for (int off = 32; off > 0; off >>= 1)
        dsum += __shfl_down(dsum, off);
    if (lane == 0) wred[w] = dsum;
    __syncthreads();
    if (t == 0) partials[bid] = (wred[0] + wred[1]) + (wred[2] + wred[3]);
}

// ---------------------------------------------------------------------------
// Kernel 3: deterministic final reduction -> mean.
// ---------------------------------------------------------------------------
__global__ __launch_bounds__(256) void reduce_kernel(const double* __restrict__ partials,
                                                     float* __restrict__ out,
                                                     int nPart, double invCount) {
    __shared__ double red[256];
    int t = threadIdx.x;
    double s = 0.0;
    for (int i = t; i < nPart; i += 256) s += partials[i];
    red[t] = s;
    __syncthreads();
    #pragma unroll
    for (int k = 128; k > 0; k >>= 1) {
        if (t < k) red[t] += red[t + k];
        __syncthreads();
    }
    if (t == 0) out[0] = (float)(red[0] * invCount);
}

extern "C" void kernel_launch(void* const* d_in, const int* in_sizes, int n_in,
                              void* d_out, int out_size, void* d_ws, size_t ws_size,
                              hipStream_t stream) {
    const float* pred = (const float*)d_in[0];
    const int*   seg  = (const int*)d_in[1];
    float* out = (float*)d_out;

    const size_t HALF = (size_t)NBATCH * L * DDIM;
    _Float16* h        = (_Float16*)d_ws;                    // 16.78 MB
    float*    sq       = (float*)(h + HALF);                 // 64 KB
    double*   partials = (double*)(sq + NBATCH * L);         // 8.7 KB

    conv_kernel<<<NBATCH * L / 4, 256, 0, stream>>>(pred, h, sq);
    loss_kernel<<<TOTAL_BLOCKS, 256, 0, stream>>>(h, seg, sq, partials);
    reduce_kernel<<<1, 256, 0, stream>>>(partials, out, TOTAL_BLOCKS,
                                         1.0 / (double)((size_t)NBATCH * L * L));
}